// Round 1
// baseline (1944.627 us; speedup 1.0000x reference)
//
#include <hip/hip_runtime.h>
#include <hip/hip_bf16.h>

// CAGAT_MinSum_Layer_Lite: per-edge fused gather->attention->scatter-add.
// out[dst] += x_src * sigmoid(leaky_relu(W0*x_src + W1*x_dst + W2*cm + b) + cm*cp) * ms
//
// Memory-bound: 403 MB streaming (edge_index + cycle_mask), gathers/scatter hit
// the 4 MB node tables (L2-resident). Roofline ~65 us at 6.3 TB/s.

__global__ __launch_bounds__(256) void cagat_edge_kernel(
    const float* __restrict__ nf,      // node_features [N]
    const int*   __restrict__ srcs,    // edge_index[0] [E]
    const int*   __restrict__ dsts,    // edge_index[1] [E]
    const float* __restrict__ cm,      // cycle_mask [E]
    const float* __restrict__ Wp,      // [3]
    const float* __restrict__ bp,      // [1]
    const float* __restrict__ msp,     // min_sum_scaler [1]
    const float* __restrict__ cpp_,    // cycle_penalty [1]
    float*       __restrict__ out,     // [N], pre-zeroed
    int E)
{
    const float W0 = Wp[0], W1 = Wp[1], W2 = Wp[2];
    const float bb = bp[0];
    const float ms = msp[0];
    const float cp = cpp_[0];

    const int i    = blockIdx.x * blockDim.x + threadIdx.x;
    const int base = i << 2;

    if (base + 3 < E) {
        // 16B/lane vectorized streaming loads
        const int4   s4 = *(const int4*)  (srcs + base);
        const int4   d4 = *(const int4*)  (dsts + base);
        const float4 c4 = *(const float4*)(cm   + base);

        const int   s[4] = {s4.x, s4.y, s4.z, s4.w};
        const int   d[4] = {d4.x, d4.y, d4.z, d4.w};
        const float c[4] = {c4.x, c4.y, c4.z, c4.w};

#pragma unroll
        for (int k = 0; k < 4; ++k) {
            const float xs  = nf[s[k]];
            const float xd  = nf[d[k]];
            float raw = fmaf(xs, W0, fmaf(xd, W1, fmaf(c[k], W2, bb)));
            raw = (raw > 0.0f) ? raw : 0.01f * raw;          // leaky_relu
            raw = fmaf(c[k], cp, raw);
            // sigmoid via v_exp_f32 + v_rcp_f32 (approx; threshold 0.32 >> 1ulp)
            const float att = __builtin_amdgcn_rcpf(1.0f + __expf(-raw));
            const float msg = xs * att * ms;
            atomicAdd(out + d[k], msg);
        }
    } else if (base < E) {
        // tail (E % 4 != 0 safety; E = 2^25 so normally unreached)
        for (int e = base; e < E; ++e) {
            const float xs = nf[srcs[e]];
            const float xd = nf[dsts[e]];
            const float cc = cm[e];
            float raw = fmaf(xs, W0, fmaf(xd, W1, fmaf(cc, W2, bb)));
            raw = (raw > 0.0f) ? raw : 0.01f * raw;
            raw = fmaf(cc, cp, raw);
            const float att = __builtin_amdgcn_rcpf(1.0f + __expf(-raw));
            atomicAdd(out + dsts[e], xs * att * ms);
        }
    }
}

extern "C" void kernel_launch(void* const* d_in, const int* in_sizes, int n_in,
                              void* d_out, int out_size, void* d_ws, size_t ws_size,
                              hipStream_t stream) {
    const float* nf   = (const float*)d_in[0];
    const int*   eidx = (const int*)  d_in[1];   // [2, E] row-major: src then dst
    const float* cm   = (const float*)d_in[2];
    const float* W    = (const float*)d_in[3];
    const float* b    = (const float*)d_in[4];
    const float* ms   = (const float*)d_in[5];
    const float* cp   = (const float*)d_in[6];
    float*       out  = (float*)d_out;

    const int E = in_sizes[2];                   // cycle_mask length == n_edges
    const int* srcs = eidx;
    const int* dsts = eidx + E;

    // Harness re-poisons d_out to 0xAA before every timed launch — zero it.
    hipMemsetAsync(d_out, 0, (size_t)out_size * sizeof(float), stream);

    const int threads = 256;
    const int nthread = (E + 3) / 4;
    const int blocks  = (nthread + threads - 1) / threads;
    cagat_edge_kernel<<<blocks, threads, 0, stream>>>(
        nf, srcs, dsts, cm, W, b, ms, cp, out, E);
}

// Round 2
// 1770.526 us; speedup vs baseline: 1.0983x; 1.0983x over previous
//
#include <hip/hip_runtime.h>
#include <hip/hip_bf16.h>

// CAGAT_MinSum_Layer_Lite — bucketed two-phase scatter-add.
//
// Round-1 evidence: 33.5M device-scope fp32 atomicAdds execute at the memory-
// side fabric (WRITE_SIZE = 33.5M x 32B, 20.6 G atomics/s = the structural
// ceiling; VALUBusy 1.3%, HBM 13% of peak). Fix: bucket edges by dst>>10 so
// accumulation happens in LDS (per-CU) and global memory only sees streaming
// reads/writes. No global atomics anywhere.
//
// P1   : per-block bucket histogram (reads dst, 134 MB)
// scan1: per-bucket exclusive prefix over blocks (in-place on histT)
// scan2: exclusive prefix of bucket totals -> bucketBase
// P2   : recompute messages, scatter (msg,dst) records to exact slots (LDS cursors)
// P3   : per-bucket coalesced record read -> LDS fp32 accumulate -> coalesced store

#define NBLK    1024   // partition blocks (P1/P2)
#define NBUCK   1024   // buckets: bucket = dst >> 10
#define THREADS 256

__global__ __launch_bounds__(THREADS) void p1_hist(
    const int* __restrict__ dsts, int E, int epb,
    unsigned int* __restrict__ histT)
{
    __shared__ unsigned int h[NBUCK];
    for (int j = threadIdx.x; j < NBUCK; j += THREADS) h[j] = 0u;
    __syncthreads();

    const int blk = blockIdx.x;
    const int start = blk * epb;
    const int end   = min(E, start + epb);
    const int n     = end - start;
    const int nvec  = n >> 2;

    for (int i = threadIdx.x; i < nvec; i += THREADS) {
        const int4 d4 = *(const int4*)(dsts + start + (i << 2));
        atomicAdd(&h[d4.x >> 10], 1u);
        atomicAdd(&h[d4.y >> 10], 1u);
        atomicAdd(&h[d4.z >> 10], 1u);
        atomicAdd(&h[d4.w >> 10], 1u);
    }
    for (int e = start + (nvec << 2) + threadIdx.x; e < end; e += THREADS)
        atomicAdd(&h[dsts[e] >> 10], 1u);

    __syncthreads();
    for (int j = threadIdx.x; j < NBUCK; j += THREADS)
        histT[(size_t)j * NBLK + blk] = h[j];
}

// One block per bucket: exclusive prefix over the NBLK per-block counts,
// in place (block b owns row b). totals[b] = row sum.
__global__ __launch_bounds__(THREADS) void p_scan1(
    unsigned int* __restrict__ histT, unsigned int* __restrict__ totals)
{
    const int b = blockIdx.x;
    unsigned int* row = histT + (size_t)b * NBLK;
    const int t = threadIdx.x;

    uint4 c = *(uint4*)(row + (t << 2));      // NBLK = 256*4
    const unsigned s0 = 0u;
    const unsigned s1 = c.x;
    const unsigned s2 = c.x + c.y;
    const unsigned s3 = c.x + c.y + c.z;
    const unsigned tsum = s3 + c.w;

    __shared__ unsigned int ls[THREADS];
    ls[t] = tsum;
    __syncthreads();
    for (int off = 1; off < THREADS; off <<= 1) {
        unsigned tmp = 0u;
        if (t >= off) tmp = ls[t - off];
        __syncthreads();
        if (t >= off) ls[t] += tmp;
        __syncthreads();
    }
    const unsigned base = (t == 0) ? 0u : ls[t - 1];

    uint4 o;
    o.x = base + s0; o.y = base + s1; o.z = base + s2; o.w = base + s3;
    *(uint4*)(row + (t << 2)) = o;

    if (t == 0) totals[b] = ls[THREADS - 1];
}

__global__ __launch_bounds__(NBUCK) void p_scan2(
    const unsigned int* __restrict__ totals, unsigned int* __restrict__ bucketBase)
{
    __shared__ unsigned int ls[NBUCK];
    const int t = threadIdx.x;
    ls[t] = totals[t];
    __syncthreads();
    for (int off = 1; off < NBUCK; off <<= 1) {
        unsigned tmp = 0u;
        if (t >= off) tmp = ls[t - off];
        __syncthreads();
        if (t >= off) ls[t] += tmp;
        __syncthreads();
    }
    bucketBase[t] = (t == 0) ? 0u : ls[t - 1];
}

__global__ __launch_bounds__(THREADS) void p2_partition(
    const float* __restrict__ nf,
    const int*   __restrict__ srcs,
    const int*   __restrict__ dsts,
    const float* __restrict__ cm,
    const float* __restrict__ Wp, const float* __restrict__ bp,
    const float* __restrict__ msp, const float* __restrict__ cpp_,
    const unsigned int* __restrict__ relT,        // scanned histT
    const unsigned int* __restrict__ bucketBase,
    uint2* __restrict__ recs, int E, int epb)
{
    __shared__ unsigned int cur[NBUCK];
    const int blk = blockIdx.x;
    for (int j = threadIdx.x; j < NBUCK; j += THREADS)
        cur[j] = bucketBase[j] + relT[(size_t)j * NBLK + blk];
    __syncthreads();

    const float W0 = Wp[0], W1 = Wp[1], W2 = Wp[2];
    const float bb = bp[0], ms = msp[0], cp = cpp_[0];

    const int start = blk * epb;
    const int end   = min(E, start + epb);
    const int n     = end - start;
    const int nvec  = n >> 2;

    for (int i = threadIdx.x; i < nvec; i += THREADS) {
        const int base = start + (i << 2);
        const int4   s4 = *(const int4*)  (srcs + base);
        const int4   d4 = *(const int4*)  (dsts + base);
        const float4 c4 = *(const float4*)(cm   + base);
        const int   s[4] = {s4.x, s4.y, s4.z, s4.w};
        const int   d[4] = {d4.x, d4.y, d4.z, d4.w};
        const float c[4] = {c4.x, c4.y, c4.z, c4.w};
#pragma unroll
        for (int k = 0; k < 4; ++k) {
            const float xs = nf[s[k]];
            const float xd = nf[d[k]];
            float raw = fmaf(xs, W0, fmaf(xd, W1, fmaf(c[k], W2, bb)));
            raw = (raw > 0.0f) ? raw : 0.01f * raw;
            raw = fmaf(c[k], cp, raw);
            const float att = __builtin_amdgcn_rcpf(1.0f + __expf(-raw));
            const float msg = xs * att * ms;
            const unsigned pos = atomicAdd(&cur[d[k] >> 10], 1u);   // LDS
            recs[pos] = make_uint2(__float_as_uint(msg), (unsigned)d[k]);
        }
    }
    for (int e = start + (nvec << 2) + threadIdx.x; e < end; e += THREADS) {
        const float xs = nf[srcs[e]];
        const float xd = nf[dsts[e]];
        const float cc = cm[e];
        float raw = fmaf(xs, W0, fmaf(xd, W1, fmaf(cc, W2, bb)));
        raw = (raw > 0.0f) ? raw : 0.01f * raw;
        raw = fmaf(cc, cp, raw);
        const float att = __builtin_amdgcn_rcpf(1.0f + __expf(-raw));
        const float msg = xs * att * ms;
        const unsigned pos = atomicAdd(&cur[dsts[e] >> 10], 1u);
        recs[pos] = make_uint2(__float_as_uint(msg), (unsigned)dsts[e]);
    }
}

__global__ __launch_bounds__(THREADS) void p3_reduce(
    const uint2* __restrict__ recs,
    const unsigned int* __restrict__ totals,
    const unsigned int* __restrict__ bucketBase,
    float* __restrict__ out, int N)
{
    __shared__ float acc[1024];
    const int b = blockIdx.x;
    for (int j = threadIdx.x; j < 1024; j += THREADS) acc[j] = 0.0f;
    __syncthreads();

    const unsigned cnt = totals[b];
    const unsigned s0  = bucketBase[b];
    for (unsigned k = threadIdx.x; k < cnt; k += THREADS) {
        const uint2 r = recs[s0 + k];
        atomicAdd(&acc[r.y & 1023u], __uint_as_float(r.x));   // LDS fp32
    }
    __syncthreads();

    const int nb = b << 10;
    for (int j = threadIdx.x; j < 1024; j += THREADS) {
        const int id = nb + j;
        if (id < N) out[id] = acc[j];
    }
}

// ---- fallback (round-1 kernel) if ws_size is too small ----
__global__ __launch_bounds__(THREADS) void cagat_atomic_fallback(
    const float* __restrict__ nf, const int* __restrict__ srcs,
    const int* __restrict__ dsts, const float* __restrict__ cm,
    const float* __restrict__ Wp, const float* __restrict__ bp,
    const float* __restrict__ msp, const float* __restrict__ cpp_,
    float* __restrict__ out, int E)
{
    const float W0 = Wp[0], W1 = Wp[1], W2 = Wp[2];
    const float bb = bp[0], ms = msp[0], cp = cpp_[0];
    const int i = blockIdx.x * blockDim.x + threadIdx.x;
    for (int e = i; e < E; e += gridDim.x * blockDim.x) {
        const float xs = nf[srcs[e]];
        const float xd = nf[dsts[e]];
        const float cc = cm[e];
        float raw = fmaf(xs, W0, fmaf(xd, W1, fmaf(cc, W2, bb)));
        raw = (raw > 0.0f) ? raw : 0.01f * raw;
        raw = fmaf(cc, cp, raw);
        const float att = __builtin_amdgcn_rcpf(1.0f + __expf(-raw));
        atomicAdd(out + dsts[e], xs * att * ms);
    }
}

extern "C" void kernel_launch(void* const* d_in, const int* in_sizes, int n_in,
                              void* d_out, int out_size, void* d_ws, size_t ws_size,
                              hipStream_t stream) {
    const float* nf   = (const float*)d_in[0];
    const int*   eidx = (const int*)  d_in[1];   // [2, E]: src row then dst row
    const float* cm   = (const float*)d_in[2];
    const float* W    = (const float*)d_in[3];
    const float* b    = (const float*)d_in[4];
    const float* ms   = (const float*)d_in[5];
    const float* cp   = (const float*)d_in[6];
    float*       out  = (float*)d_out;

    const int E = in_sizes[2];
    const int N = in_sizes[0];
    const int* srcs = eidx;
    const int* dsts = eidx + E;

    const size_t recs_bytes = (size_t)E * 8u;
    const size_t hist_bytes = (size_t)NBUCK * NBLK * 4u;
    const size_t tot_bytes  = (size_t)NBUCK * 4u;
    const size_t need = recs_bytes + hist_bytes + 2u * tot_bytes;

    if (ws_size < need) {
        // not enough scratch: proven atomic path
        hipMemsetAsync(d_out, 0, (size_t)out_size * sizeof(float), stream);
        cagat_atomic_fallback<<<8192, THREADS, 0, stream>>>(
            nf, srcs, dsts, cm, W, b, ms, cp, out, E);
        return;
    }

    char* wsb = (char*)d_ws;
    uint2*        recs       = (uint2*)wsb;
    unsigned int* histT      = (unsigned int*)(wsb + recs_bytes);
    unsigned int* totals     = (unsigned int*)(wsb + recs_bytes + hist_bytes);
    unsigned int* bucketBase = (unsigned int*)(wsb + recs_bytes + hist_bytes + tot_bytes);

    const int epb = (E + NBLK - 1) / NBLK;       // 32768 for E=2^25

    p1_hist<<<NBLK, THREADS, 0, stream>>>(dsts, E, epb, histT);
    p_scan1<<<NBUCK, THREADS, 0, stream>>>(histT, totals);
    p_scan2<<<1, NBUCK, 0, stream>>>(totals, bucketBase);
    p2_partition<<<NBLK, THREADS, 0, stream>>>(
        nf, srcs, dsts, cm, W, b, ms, cp, histT, bucketBase, recs, E, epb);

    const int nOutBlocks = (N + 1023) / 1024;    // 977
    p3_reduce<<<nOutBlocks, THREADS, 0, stream>>>(recs, totals, bucketBase, out, N);
}